// Round 2
// baseline (332.059 us; speedup 1.0000x reference)
//
#include <hip/hip_runtime.h>

// ---------------------------------------------------------------------------
// Round 8: flash rebuilt BARRIER-FREE. K/V are L2-resident (8 heads x 512 KB
// = 4 MB per XCD via blockIdx%8 == head%8); LDS staging of L2-fit data was
// pure overhead (common-mistake #7). Each wave loads MFMA K/V fragments
// directly from global (coalesced 16B/lane, identical operand semantics to
// the old swizzled-LDS path). No __syncthreads anywhere; only per-wave P
// bounce through 4 KB LDS (lgkmcnt-ordered). 2048 single-q-tile blocks,
// longest-first; __launch_bounds__(128,3) -> >=12 waves/CU co-resident.
// B=4, S=2048, NH=16, DH=64, E=1024. fp32 I/O, bf16 compute, fp32 accum.
// ---------------------------------------------------------------------------

typedef __attribute__((ext_vector_type(8))) short short8;
typedef __attribute__((ext_vector_type(4))) float floatx4;

#define SCL 0.1803368801111244f   // (1/8) * log2(e), folded into Q projection

__device__ __forceinline__ unsigned short f2bf(float f) {
  unsigned int x = __float_as_uint(f);
  x += 0x7fffu + ((x >> 16) & 1u);   // RNE
  return (unsigned short)(x >> 16);
}

__device__ __forceinline__ void gload_lds16(const unsigned short* g, unsigned short* lds) {
  __builtin_amdgcn_global_load_lds(
      (const __attribute__((address_space(1))) void*)g,
      (__attribute__((address_space(3))) void*)lds, 16, 0, 0);
}

// ---------------- fused prep: cvt_x + W_QKV transpose + W_O transpose ------
__global__ __launch_bounds__(256) void prep_kernel(
    const float* __restrict__ X,  unsigned short* __restrict__ Xb,
    const float* __restrict__ Wq, const float* __restrict__ Wk,
    const float* __restrict__ Wv, unsigned short* __restrict__ Bt,
    const float* __restrict__ Wo, unsigned short* __restrict__ Wt)
{
  __shared__ unsigned short T[64 * 72];
  const int bid = blockIdx.x, t = threadIdx.x;
  if (bid < 8192) {                                  // ---- x fp32 -> bf16
    int idx = ((bid << 8) + t) << 2;
    float4 f = *(const float4*)(X + idx);
    unsigned short u[4] = { f2bf(f.x), f2bf(f.y), f2bf(f.z), f2bf(f.w) };
    *(uint2*)(Xb + idx) = *(uint2*)u;
  } else if (bid < 8960) {                           // ---- W_{Q,K,V} transpose
    int b2 = bid - 8192;
    int e0 = (b2 & 15) << 6, nn = (b2 >> 4) & 15, proj = b2 >> 8;
    const float* W = (proj == 0) ? Wq : (proj == 1) ? Wk : Wv;
    const float* src = W + ((size_t)nn << 16) + ((size_t)e0 << 6);
#pragma unroll
    for (int rnd = 0; rnd < 4; ++rnd) {
      int off = (rnd << 10) + (t << 2);
      float4 f = *(const float4*)(src + off);
      int r = off >> 6, h = off & 63;
      T[r * 72 + h]     = f2bf(f.x);
      T[r * 72 + h + 1] = f2bf(f.y);
      T[r * 72 + h + 2] = f2bf(f.z);
      T[r * 72 + h + 3] = f2bf(f.w);
    }
    __syncthreads();
    const int h = t >> 2, ck = t & 3;
    size_t orow = ((size_t)((proj << 10) + (nn << 6) + h) << 10) + e0 + (ck << 4);
#pragma unroll
    for (int g = 0; g < 2; ++g) {
      unsigned short v[8];
#pragma unroll
      for (int j = 0; j < 8; ++j) v[j] = T[((ck << 4) + (g << 3) + j) * 72 + h];
      *(int4*)(Bt + orow + (g << 3)) = *(int4*)v;
    }
  } else {                                           // ---- W_O transpose
    int b2 = bid - 8960;
    int e0 = (b2 & 15) << 6, k0 = (b2 >> 4) << 6;
#pragma unroll
    for (int rnd = 0; rnd < 4; ++rnd) {
      int r = (rnd << 4) + (t >> 4);
      int c = (t & 15) << 2;
      float4 f = *(const float4*)(Wo + ((size_t)(k0 + r) << 10) + e0 + c);
      T[r * 72 + c]     = f2bf(f.x);
      T[r * 72 + c + 1] = f2bf(f.y);
      T[r * 72 + c + 2] = f2bf(f.z);
      T[r * 72 + c + 3] = f2bf(f.w);
    }
    __syncthreads();
    const int i = t >> 2, ck = t & 3;
    size_t orow = ((size_t)(e0 + i) << 10) + k0 + (ck << 4);
#pragma unroll
    for (int g = 0; g < 2; ++g) {
      unsigned short v[8];
#pragma unroll
      for (int j = 0; j < 8; ++j) v[j] = T[((ck << 4) + (g << 3) + j) * 72 + i];
      *(int4*)(Wt + orow + (g << 3)) = *(int4*)v;
    }
  }
}

// ---------------- 128x128 MFMA GEMM, BK=64 (round-5, kept) -----------------
template <int MODE>
__global__ __launch_bounds__(256) void gemm128_kernel(
    const unsigned short* __restrict__ A,
    const unsigned short* __restrict__ Bt,
    const float* __restrict__ b0, const float* __restrict__ b1,
    const float* __restrict__ b2,
    unsigned short* __restrict__ Oq, unsigned short* __restrict__ Ok,
    unsigned short* __restrict__ Ov, float* __restrict__ Of)
{
  const int K = 1024;
  __shared__ __align__(16) unsigned short As[8192];   // [128][64] swizzled
  __shared__ __align__(16) unsigned short Bs[8192];
  const int tid = threadIdx.x;
  const int l   = tid & 63, w = tid >> 6;
  const int l15 = l & 15,  lg = l >> 4;
  const int mo  = (w >> 1) << 6, no = (w & 1) << 6;
  const int m0  = blockIdx.y << 7, n0 = blockIdx.x << 7;
  const int srow = l >> 3;
  const int gblk = ((l & 7) ^ srow) << 3;
  const int rsw  = l15 & 7;

  floatx4 acc[4][4];
#pragma unroll
  for (int i = 0; i < 4; ++i)
#pragma unroll
    for (int j = 0; j < 4; ++j) acc[i][j] = (floatx4){0.f, 0.f, 0.f, 0.f};

  for (int k0 = 0; k0 < K; k0 += 64) {
    __syncthreads();
#pragma unroll
    for (int s = 0; s < 4; ++s) {
      const int br = (s << 5) + (w << 3);
      gload_lds16(A  + (size_t)(m0 + br + srow) * K + k0 + gblk, &As[br << 6]);
      gload_lds16(Bt + (size_t)(n0 + br + srow) * K + k0 + gblk, &Bs[br << 6]);
    }
    __syncthreads();
#pragma unroll
    for (int kh = 0; kh < 2; ++kh) {
      const int bo = (((kh << 2) + lg) ^ rsw) << 3;
      short8 af[4], bf[4];
#pragma unroll
      for (int mc = 0; mc < 4; ++mc)
        af[mc] = *(const short8*)&As[((mo + (mc << 4) + l15) << 6) + bo];
#pragma unroll
      for (int nc = 0; nc < 4; ++nc)
        bf[nc] = *(const short8*)&Bs[((no + (nc << 4) + l15) << 6) + bo];
#pragma unroll
      for (int mc = 0; mc < 4; ++mc)
#pragma unroll
        for (int nc = 0; nc < 4; ++nc)
          acc[mc][nc] = __builtin_amdgcn_mfma_f32_16x16x32_bf16(af[mc], bf[nc], acc[mc][nc], 0, 0, 0);
    }
  }

#pragma unroll
  for (int nc = 0; nc < 4; ++nc) {
    int c = n0 + no + (nc << 4) + l15;
    if (MODE == 1) {
      float bv = b0[c];
#pragma unroll
      for (int mc = 0; mc < 4; ++mc)
#pragma unroll
        for (int r = 0; r < 4; ++r) {
          int m = m0 + mo + (mc << 4) + (lg << 2) + r;
          Of[((size_t)m << 10) + c] = acc[mc][nc][r] + bv;
        }
    } else {
      int proj = c >> 10, cc = c & 1023;         // wave-uniform
      int hn = cc >> 6, h = cc & 63;
      const float* bp = (proj == 0) ? b0 : (proj == 1) ? b1 : b2;
      float bv = bp[cc];
      float sc = (proj == 0) ? SCL : 1.0f;
      if (proj < 2) {
        unsigned short* O = (proj == 0) ? Oq : Ok;
#pragma unroll
        for (int mc = 0; mc < 4; ++mc)
#pragma unroll
          for (int r = 0; r < 4; ++r) {
            int m = m0 + mo + (mc << 4) + (lg << 2) + r;
            int bb = m >> 11, ss = m & 2047;
            O[((((size_t)(bb << 4) + hn) << 11) + ss) * 64 + h] = f2bf((acc[mc][nc][r] + bv) * sc);
          }
      } else {                                   // V transposed: Vt[b][n][d][s]
#pragma unroll
        for (int mc = 0; mc < 4; ++mc) {
          int m = m0 + mo + (mc << 4) + (lg << 2);
          int bb = m >> 11, ss = m & 2047;
          unsigned short p0 = f2bf(acc[mc][nc][0] + bv);
          unsigned short p1 = f2bf(acc[mc][nc][1] + bv);
          unsigned short p2 = f2bf(acc[mc][nc][2] + bv);
          unsigned short p3 = f2bf(acc[mc][nc][3] + bv);
          uint2 pk;
          pk.x = (unsigned int)p0 | ((unsigned int)p1 << 16);
          pk.y = (unsigned int)p2 | ((unsigned int)p3 << 16);
          *(uint2*)&Ov[((((size_t)(bb << 4) + hn) << 6) + h) * 2048 + ss] = pk;
        }
      }
    }
  }
}

// ---------------- MFMA flash attention v7: barrier-free, L2-direct ---------
// 2048 blocks x 128 threads; block = one 64-row q-tile (2 waves x 32 rows).
// qt = 31-(x>>6): longest blocks dispatched first (tail packing).
// head = x&63 -> XCD = x%8 = head%8: all 32 q-tiles of a head on one XCD;
// 8 heads x 512 KB K/V = 4 MB = L2/XCD. K/V fragments loaded straight from
// global (L2-hit), no LDS staging, NO barriers. Only LDS: per-wave P bounce.
__global__ __launch_bounds__(128, 3) void flash7_kernel(
    const unsigned short* __restrict__ Q,   // [B,N,S,D], pre-scaled by SCL
    const unsigned short* __restrict__ K,   // [B,N,S,D]
    const unsigned short* __restrict__ Vt,  // [B,N,D,S]
    unsigned short* __restrict__ Z)         // [B,S,N*D]
{
  __shared__ __align__(16) unsigned short Ps[4096];   // 2 waves x [32 q][64 k] swz

  const int tid = threadIdx.x;
  const int l   = tid & 63, w = tid >> 6;             // w in {0,1}
  const int l15 = l & 15,  lg = l >> 4;
  const int x    = blockIdx.x;
  const int qt   = 31 - (x >> 6);                     // q-tile (longest first)
  const int head = x & 63;
  const int n = head & 15, b = head >> 4;
  const size_t hoff = (size_t)head << 17;
  const unsigned short* Qh = Q + hoff;
  const unsigned short* Kh = K + hoff;
  const unsigned short* Vh = Vt + hoff;
  unsigned short* Psw = Ps + (w << 11);

  const int swz = l15 & 7;
  // Ps swizzle (shorts, row-local; row&7 == swz):
  //  write key-base mc*16+lg*4 -> chunk16 = 2mc+(lg>>1), half8 = lg&1
  //  read  key-base kc*32+lg*8 -> chunk16 = 4kc+lg
  int pwofs[4], profs[2];
#pragma unroll
  for (int mc = 0; mc < 4; ++mc)
    pwofs[mc] = ((((mc << 1) + (lg >> 1)) ^ swz) << 3) + ((lg & 1) << 2);
#pragma unroll
  for (int kc = 0; kc < 2; ++kc)
    profs[kc] = (((kc << 2) + lg) ^ swz) << 3;

  short8 onef;
#pragma unroll
  for (int i = 0; i < 8; ++i) onef[i] = (short)0x3F80;   // bf16 1.0

  const int q0w = (qt << 6) + (w << 5);

  short8 qf[2][2];
#pragma unroll
  for (int qc = 0; qc < 2; ++qc)
#pragma unroll
    for (int dh = 0; dh < 2; ++dh)
      qf[qc][dh] = *(const short8*)(Qh + (size_t)(q0w + (qc << 4) + l15) * 64 + (dh << 5) + (lg << 3));

  floatx4 acc_o[2][4], acc_l[2];
#pragma unroll
  for (int qc = 0; qc < 2; ++qc) {
    acc_l[qc] = (floatx4){0.f, 0.f, 0.f, 0.f};
#pragma unroll
    for (int dc = 0; dc < 4; ++dc) acc_o[qc][dc] = (floatx4){0.f, 0.f, 0.f, 0.f};
  }

  const int nkt = qt + 1;
  for (int kt = 0; kt < nkt; ++kt) {
    const int k0 = kt << 6;

    // ---- K fragments straight from L2: K[key = k0+mc*16+l15][d = dh*32+lg*8]
    short8 ak[2][4];
#pragma unroll
    for (int dh = 0; dh < 2; ++dh)
#pragma unroll
      for (int mc = 0; mc < 4; ++mc)
        ak[dh][mc] = *(const short8*)(Kh + (size_t)(k0 + (mc << 4) + l15) * 64 + (dh << 5) + (lg << 3));

    // ---- S^T[key][q] = K * Q^T ----
    floatx4 s0[4], s1[4];
#pragma unroll
    for (int mc = 0; mc < 4; ++mc) {
      s0[mc] = (floatx4){0.f, 0.f, 0.f, 0.f};
      s1[mc] = (floatx4){0.f, 0.f, 0.f, 0.f};
    }
    __builtin_amdgcn_s_setprio(1);
#pragma unroll
    for (int dh = 0; dh < 2; ++dh)
#pragma unroll
      for (int mc = 0; mc < 4; ++mc) {
        s0[mc] = __builtin_amdgcn_mfma_f32_16x16x32_bf16(ak[dh][mc], qf[0][dh], s0[mc], 0, 0, 0);
        s1[mc] = __builtin_amdgcn_mfma_f32_16x16x32_bf16(ak[dh][mc], qf[1][dh], s1[mc], 0, 0, 0);
      }
    __builtin_amdgcn_s_setprio(0);

    // ---- V fragments issued now; latency hides under exp/pack ----
    // Vt[d = dc*16+l15][k0 + kc*32 + lg*8]
    short8 vb[2][4];
#pragma unroll
    for (int kc = 0; kc < 2; ++kc)
#pragma unroll
      for (int dc = 0; dc < 4; ++dc)
        vb[kc][dc] = *(const short8*)(Vh + (size_t)((dc << 4) + l15) * 2048 + k0 + (kc << 5) + (lg << 3));

    // ---- p = 2^s; mask only on diagonal tiles; truncation-pack ----
    const bool needmask = (k0 + 63 > q0w);
#pragma unroll
    for (int qc = 0; qc < 2; ++qc) {
      const int qg = q0w + (qc << 4) + l15;
      const int rbase = ((qc << 4) + l15) << 6;
#pragma unroll
      for (int mc = 0; mc < 4; ++mc) {
        float p[4];
#pragma unroll
        for (int r = 0; r < 4; ++r) {
          float e = exp2f(qc ? s1[mc][r] : s0[mc][r]);
          if (needmask) {
            int key = k0 + (mc << 4) + (lg << 2) + r;
            e = (key > qg) ? 0.f : e;
          }
          p[r] = e;
        }
        uint2 pk;
        pk.x = (__float_as_uint(p[1]) & 0xFFFF0000u) | (__float_as_uint(p[0]) >> 16);
        pk.y = (__float_as_uint(p[3]) & 0xFFFF0000u) | (__float_as_uint(p[2]) >> 16);
        *(uint2*)&Psw[rbase + pwofs[mc]] = pk;
      }
    }

    // ---- PV: O += P*V ; l += P*ones ----
    short8 pa[2][2];
#pragma unroll
    for (int qc = 0; qc < 2; ++qc) {
      const int rbase = ((qc << 4) + l15) << 6;
#pragma unroll
      for (int kc = 0; kc < 2; ++kc)
        pa[qc][kc] = *(const short8*)&Psw[rbase + profs[kc]];
    }
    __builtin_amdgcn_s_setprio(1);
#pragma unroll
    for (int kc = 0; kc < 2; ++kc) {
#pragma unroll
      for (int dc = 0; dc < 4; ++dc) {
        acc_o[0][dc] = __builtin_amdgcn_mfma_f32_16x16x32_bf16(pa[0][kc], vb[kc][dc], acc_o[0][dc], 0, 0, 0);
        acc_o[1][dc] = __builtin_amdgcn_mfma_f32_16x16x32_bf16(pa[1][kc], vb[kc][dc], acc_o[1][dc], 0, 0, 0);
      }
      acc_l[0] = __builtin_amdgcn_mfma_f32_16x16x32_bf16(pa[0][kc], onef, acc_l[0], 0, 0, 0);
      acc_l[1] = __builtin_amdgcn_mfma_f32_16x16x32_bf16(pa[1][kc], onef, acc_l[1], 0, 0, 0);
    }
    __builtin_amdgcn_s_setprio(0);
  }

  // ---- epilogue: Z = O / l ----
#pragma unroll
  for (int qc = 0; qc < 2; ++qc) {
    floatx4 inv;
#pragma unroll
    for (int r = 0; r < 4; ++r) inv[r] = 1.f / acc_l[qc][r];
#pragma unroll
    for (int dc = 0; dc < 4; ++dc)
#pragma unroll
      for (int r = 0; r < 4; ++r) {
        int qg = q0w + (qc << 4) + (lg << 2) + r;
        Z[(((size_t)b << 11) + qg) * 1024 + (n << 6) + (dc << 4) + l15] =
            f2bf(acc_o[qc][dc][r] * inv[r]);
      }
  }
}

// ---------------------------------------------------------------------------
extern "C" void kernel_launch(void* const* d_in, const int* in_sizes, int n_in,
                              void* d_out, int out_size, void* d_ws, size_t ws_size,
                              hipStream_t stream) {
  const float* x   = (const float*)d_in[0];
  const float* W_Q = (const float*)d_in[1];
  const float* b_Q = (const float*)d_in[2];
  const float* W_K = (const float*)d_in[3];
  const float* b_K = (const float*)d_in[4];
  const float* W_V = (const float*)d_in[5];
  const float* b_V = (const float*)d_in[6];
  const float* W_O = (const float*)d_in[7];
  const float* b_O = (const float*)d_in[8];
  float* out = (float*)d_out;

  unsigned short* ws    = (unsigned short*)d_ws;
  unsigned short* BtQKV = ws;                        // [3072][1024]
  unsigned short* Wo_t  = BtQKV + (3u << 20);        // [1024][1024]
  unsigned short* Xb    = Wo_t + (1u << 20);         // [8192][1024]
  unsigned short* Qb    = Xb + (8u << 20);           // [B,N,S,D]
  unsigned short* Kb    = Qb + (8u << 20);
  unsigned short* Vtb   = Kb + (8u << 20);           // [B,N,D,S]
  unsigned short* Zb    = Vtb + (8u << 20);          // [B,S,N*D]

  prep_kernel<<<9216, 256, 0, stream>>>(x, Xb, W_Q, W_K, W_V, BtQKV, W_O, Wo_t);

  gemm128_kernel<0><<<dim3(24, 64), 256, 0, stream>>>(
      Xb, BtQKV, b_Q, b_K, b_V, Qb, Kb, Vtb, nullptr);

  flash7_kernel<<<2048, 128, 0, stream>>>(Qb, Kb, Vtb, Zb);

  gemm128_kernel<1><<<dim3(8, 64), 256, 0, stream>>>(
      Zb, Wo_t, b_O, nullptr, nullptr, nullptr, nullptr, nullptr, out);
}

// Round 3
// 274.870 us; speedup vs baseline: 1.2081x; 1.2081x over previous
//
#include <hip/hip_runtime.h>

// ---------------------------------------------------------------------------
// Round 9: revert round-8's L2-direct experiment (L2 latency serialization:
// 151us, MfmaUtil 10.5). Back to round-7's LDS-staged 2-phase pipeline, but
// with 4-wave (256-thread) blocks on 128-row q-tiles: K/V staging shared by
// 4 waves, LDS 40KB -> 4 blocks/CU = 16 waves/CU (2x round 7's 8-wave cap,
// which was the real limiter: grid 1024 x 2 waves = 25% occupancy ceiling).
// Wave w skips fully-masked k-tiles (uniform) -> useful MFMA identical.
// B=4, S=2048, NH=16, DH=64, E=1024. fp32 I/O, bf16 compute, fp32 accum.
// ---------------------------------------------------------------------------

typedef __attribute__((ext_vector_type(8))) short short8;
typedef __attribute__((ext_vector_type(4))) float floatx4;

#define SCL 0.1803368801111244f   // (1/8) * log2(e), folded into Q projection

__device__ __forceinline__ unsigned short f2bf(float f) {
  unsigned int x = __float_as_uint(f);
  x += 0x7fffu + ((x >> 16) & 1u);   // RNE
  return (unsigned short)(x >> 16);
}

__device__ __forceinline__ void gload_lds16(const unsigned short* g, unsigned short* lds) {
  __builtin_amdgcn_global_load_lds(
      (const __attribute__((address_space(1))) void*)g,
      (__attribute__((address_space(3))) void*)lds, 16, 0, 0);
}

// ---------------- fused prep: cvt_x + W_QKV transpose + W_O transpose ------
__global__ __launch_bounds__(256) void prep_kernel(
    const float* __restrict__ X,  unsigned short* __restrict__ Xb,
    const float* __restrict__ Wq, const float* __restrict__ Wk,
    const float* __restrict__ Wv, unsigned short* __restrict__ Bt,
    const float* __restrict__ Wo, unsigned short* __restrict__ Wt)
{
  __shared__ unsigned short T[64 * 72];
  const int bid = blockIdx.x, t = threadIdx.x;
  if (bid < 8192) {                                  // ---- x fp32 -> bf16
    int idx = ((bid << 8) + t) << 2;
    float4 f = *(const float4*)(X + idx);
    unsigned short u[4] = { f2bf(f.x), f2bf(f.y), f2bf(f.z), f2bf(f.w) };
    *(uint2*)(Xb + idx) = *(uint2*)u;
  } else if (bid < 8960) {                           // ---- W_{Q,K,V} transpose
    int b2 = bid - 8192;
    int e0 = (b2 & 15) << 6, nn = (b2 >> 4) & 15, proj = b2 >> 8;
    const float* W = (proj == 0) ? Wq : (proj == 1) ? Wk : Wv;
    const float* src = W + ((size_t)nn << 16) + ((size_t)e0 << 6);
#pragma unroll
    for (int rnd = 0; rnd < 4; ++rnd) {
      int off = (rnd << 10) + (t << 2);
      float4 f = *(const float4*)(src + off);
      int r = off >> 6, h = off & 63;
      T[r * 72 + h]     = f2bf(f.x);
      T[r * 72 + h + 1] = f2bf(f.y);
      T[r * 72 + h + 2] = f2bf(f.z);
      T[r * 72 + h + 3] = f2bf(f.w);
    }
    __syncthreads();
    const int h = t >> 2, ck = t & 3;
    size_t orow = ((size_t)((proj << 10) + (nn << 6) + h) << 10) + e0 + (ck << 4);
#pragma unroll
    for (int g = 0; g < 2; ++g) {
      unsigned short v[8];
#pragma unroll
      for (int j = 0; j < 8; ++j) v[j] = T[((ck << 4) + (g << 3) + j) * 72 + h];
      *(int4*)(Bt + orow + (g << 3)) = *(int4*)v;
    }
  } else {                                           // ---- W_O transpose
    int b2 = bid - 8960;
    int e0 = (b2 & 15) << 6, k0 = (b2 >> 4) << 6;
#pragma unroll
    for (int rnd = 0; rnd < 4; ++rnd) {
      int r = (rnd << 4) + (t >> 4);
      int c = (t & 15) << 2;
      float4 f = *(const float4*)(Wo + ((size_t)(k0 + r) << 10) + e0 + c);
      T[r * 72 + c]     = f2bf(f.x);
      T[r * 72 + c + 1] = f2bf(f.y);
      T[r * 72 + c + 2] = f2bf(f.z);
      T[r * 72 + c + 3] = f2bf(f.w);
    }
    __syncthreads();
    const int i = t >> 2, ck = t & 3;
    size_t orow = ((size_t)(e0 + i) << 10) + k0 + (ck << 4);
#pragma unroll
    for (int g = 0; g < 2; ++g) {
      unsigned short v[8];
#pragma unroll
      for (int j = 0; j < 8; ++j) v[j] = T[((ck << 4) + (g << 3) + j) * 72 + i];
      *(int4*)(Wt + orow + (g << 3)) = *(int4*)v;
    }
  }
}

// ---------------- 128x128 MFMA GEMM, BK=64 (round-5, kept) -----------------
template <int MODE>
__global__ __launch_bounds__(256) void gemm128_kernel(
    const unsigned short* __restrict__ A,
    const unsigned short* __restrict__ Bt,
    const float* __restrict__ b0, const float* __restrict__ b1,
    const float* __restrict__ b2,
    unsigned short* __restrict__ Oq, unsigned short* __restrict__ Ok,
    unsigned short* __restrict__ Ov, float* __restrict__ Of)
{
  const int K = 1024;
  __shared__ __align__(16) unsigned short As[8192];   // [128][64] swizzled
  __shared__ __align__(16) unsigned short Bs[8192];
  const int tid = threadIdx.x;
  const int l   = tid & 63, w = tid >> 6;
  const int l15 = l & 15,  lg = l >> 4;
  const int mo  = (w >> 1) << 6, no = (w & 1) << 6;
  const int m0  = blockIdx.y << 7, n0 = blockIdx.x << 7;
  const int srow = l >> 3;
  const int gblk = ((l & 7) ^ srow) << 3;
  const int rsw  = l15 & 7;

  floatx4 acc[4][4];
#pragma unroll
  for (int i = 0; i < 4; ++i)
#pragma unroll
    for (int j = 0; j < 4; ++j) acc[i][j] = (floatx4){0.f, 0.f, 0.f, 0.f};

  for (int k0 = 0; k0 < K; k0 += 64) {
    __syncthreads();
#pragma unroll
    for (int s = 0; s < 4; ++s) {
      const int br = (s << 5) + (w << 3);
      gload_lds16(A  + (size_t)(m0 + br + srow) * K + k0 + gblk, &As[br << 6]);
      gload_lds16(Bt + (size_t)(n0 + br + srow) * K + k0 + gblk, &Bs[br << 6]);
    }
    __syncthreads();
#pragma unroll
    for (int kh = 0; kh < 2; ++kh) {
      const int bo = (((kh << 2) + lg) ^ rsw) << 3;
      short8 af[4], bf[4];
#pragma unroll
      for (int mc = 0; mc < 4; ++mc)
        af[mc] = *(const short8*)&As[((mo + (mc << 4) + l15) << 6) + bo];
#pragma unroll
      for (int nc = 0; nc < 4; ++nc)
        bf[nc] = *(const short8*)&Bs[((no + (nc << 4) + l15) << 6) + bo];
#pragma unroll
      for (int mc = 0; mc < 4; ++mc)
#pragma unroll
        for (int nc = 0; nc < 4; ++nc)
          acc[mc][nc] = __builtin_amdgcn_mfma_f32_16x16x32_bf16(af[mc], bf[nc], acc[mc][nc], 0, 0, 0);
    }
  }

#pragma unroll
  for (int nc = 0; nc < 4; ++nc) {
    int c = n0 + no + (nc << 4) + l15;
    if (MODE == 1) {
      float bv = b0[c];
#pragma unroll
      for (int mc = 0; mc < 4; ++mc)
#pragma unroll
        for (int r = 0; r < 4; ++r) {
          int m = m0 + mo + (mc << 4) + (lg << 2) + r;
          Of[((size_t)m << 10) + c] = acc[mc][nc][r] + bv;
        }
    } else {
      int proj = c >> 10, cc = c & 1023;         // wave-uniform
      int hn = cc >> 6, h = cc & 63;
      const float* bp = (proj == 0) ? b0 : (proj == 1) ? b1 : b2;
      float bv = bp[cc];
      float sc = (proj == 0) ? SCL : 1.0f;
      if (proj < 2) {
        unsigned short* O = (proj == 0) ? Oq : Ok;
#pragma unroll
        for (int mc = 0; mc < 4; ++mc)
#pragma unroll
          for (int r = 0; r < 4; ++r) {
            int m = m0 + mo + (mc << 4) + (lg << 2) + r;
            int bb = m >> 11, ss = m & 2047;
            O[((((size_t)(bb << 4) + hn) << 11) + ss) * 64 + h] = f2bf((acc[mc][nc][r] + bv) * sc);
          }
      } else {                                   // V transposed: Vt[b][n][d][s]
#pragma unroll
        for (int mc = 0; mc < 4; ++mc) {
          int m = m0 + mo + (mc << 4) + (lg << 2);
          int bb = m >> 11, ss = m & 2047;
          unsigned short p0 = f2bf(acc[mc][nc][0] + bv);
          unsigned short p1 = f2bf(acc[mc][nc][1] + bv);
          unsigned short p2 = f2bf(acc[mc][nc][2] + bv);
          unsigned short p3 = f2bf(acc[mc][nc][3] + bv);
          uint2 pk;
          pk.x = (unsigned int)p0 | ((unsigned int)p1 << 16);
          pk.y = (unsigned int)p2 | ((unsigned int)p3 << 16);
          *(uint2*)&Ov[((((size_t)(bb << 4) + hn) << 6) + h) * 2048 + ss] = pk;
        }
      }
    }
  }
}

// ---------------- MFMA flash attention v8: 4-wave, 128-row q-tiles ---------
// 1024 blocks x 256 threads (4 waves x 32 q-rows = 128-row q-tile).
// qt = 15-(x>>6): longest blocks first (LPT). head = x&63 -> XCD = head%8:
// 8 heads x 512 KB K/V = 4 MB = L2/XCD. K/V double-buffered in LDS, staged
// cooperatively by all 4 waves (4 gloads/wave/tile); next tile issued BEFORE
// compute; one vmcnt(0)+s_barrier per tile. Wave w skips fully-masked tiles
// (wave-uniform). LDS 40KB -> 4 blocks/CU = 16 waves/CU.
__global__ __launch_bounds__(256, 4) void flash8_kernel(
    const unsigned short* __restrict__ Q,   // [B,N,S,D], pre-scaled by SCL
    const unsigned short* __restrict__ K,   // [B,N,S,D]
    const unsigned short* __restrict__ Vt,  // [B,N,D,S]
    unsigned short* __restrict__ Z)         // [B,S,N*D]
{
  __shared__ __align__(16) unsigned short Ks[8192];   // 2 x [64 key][64 d] swz
  __shared__ __align__(16) unsigned short Vs[8192];   // 2 x [64 d][64 key] swz
  __shared__ __align__(16) unsigned short Ps[8192];   // 4 waves x [32 q][64 k] swz

  const int tid = threadIdx.x;
  const int l   = tid & 63, w = tid >> 6;             // w in {0,1,2,3}
  const int l15 = l & 15,  lg = l >> 4;
  const int x    = blockIdx.x;
  const int qt   = 15 - (x >> 6);                     // 128-row q-tile, longest first
  const int head = x & 63;
  const int n = head & 15, b = head >> 4;
  const size_t hoff = (size_t)head << 17;
  const unsigned short* Qh = Q + hoff;
  const unsigned short* Kh = K + hoff;
  const unsigned short* Vh = Vt + hoff;
  unsigned short* Psw = Ps + (w << 11);

  const int srow8 = l >> 3;
  const int sblk8 = ((l & 7) ^ srow8) << 3;
  const int swz   = l15 & 7;
  const int bo0   = (lg ^ swz) << 3;
  const int bo1   = ((4 + lg) ^ swz) << 3;

  // Ps swizzle (shorts, row-local; row&7 == swz):
  //  write key-base mc*16+lg*4 -> chunk16 = 2mc+(lg>>1), half8 = lg&1
  //  read  key-base kc*32+lg*8 -> chunk16 = 4kc+lg
  int pwofs[4], profs[2];
#pragma unroll
  for (int mc = 0; mc < 4; ++mc)
    pwofs[mc] = ((((mc << 1) + (lg >> 1)) ^ swz) << 3) + ((lg & 1) << 2);
#pragma unroll
  for (int kc = 0; kc < 2; ++kc)
    profs[kc] = (((kc << 2) + lg) ^ swz) << 3;

  short8 onef;
#pragma unroll
  for (int i = 0; i < 8; ++i) onef[i] = (short)0x3F80;   // bf16 1.0

  const int q0w = (qt << 7) + (w << 5);                  // wave's 32 rows

  short8 qf[2][2];
#pragma unroll
  for (int qc = 0; qc < 2; ++qc)
#pragma unroll
    for (int dh = 0; dh < 2; ++dh)
      qf[qc][dh] = *(const short8*)(Qh + (size_t)(q0w + (qc << 4) + l15) * 64 + (dh << 5) + (lg << 3));

  floatx4 acc_o[2][4], acc_l[2];
#pragma unroll
  for (int qc = 0; qc < 2; ++qc) {
    acc_l[qc] = (floatx4){0.f, 0.f, 0.f, 0.f};
#pragma unroll
    for (int dc = 0; dc < 4; ++dc) acc_o[qc][dc] = (floatx4){0.f, 0.f, 0.f, 0.f};
  }

  // ---- prologue: stage k-tile 0 into buffer 0 (segs 2w, 2w+1) ----
#pragma unroll
  for (int j = 0; j < 2; ++j) {
    const int s = (w << 1) + j;                        // segment 0..7
    gload_lds16(Kh + (size_t)((s << 3) + srow8) * 64 + sblk8, &Ks[s << 9]);
    gload_lds16(Vh + (size_t)((s << 3) + srow8) * 2048 + sblk8, &Vs[s << 9]);
  }
  asm volatile("s_waitcnt vmcnt(0)" ::: "memory");
  __builtin_amdgcn_s_barrier();

  int buf = 0;
  const int nkt = (qt << 1) + 2;                       // 64-key tiles
  for (int kt = 0; kt < nkt; ++kt) {
    const int k0 = kt << 6;

    // ---- issue next tile's staging into buf^1 (in flight during compute)
    if (kt + 1 < nkt) {
      const int nk0 = (kt + 1) << 6;
      const int nb = (buf ^ 1) << 12;
#pragma unroll
      for (int j = 0; j < 2; ++j) {
        const int s = (w << 1) + j;
        gload_lds16(Kh + (size_t)(nk0 + (s << 3) + srow8) * 64 + sblk8, &Ks[nb + (s << 9)]);
        gload_lds16(Vh + (size_t)((s << 3) + srow8) * 2048 + nk0 + sblk8, &Vs[nb + (s << 9)]);
      }
    }

    // ---- wave-uniform skip of fully-masked tiles ----
    if (k0 <= q0w + 31) {
      const int cb = buf << 12;

      // ---- S^T[key][q] = K * Q^T ----
      floatx4 s0[4], s1[4];
#pragma unroll
      for (int mc = 0; mc < 4; ++mc) {
        s0[mc] = (floatx4){0.f, 0.f, 0.f, 0.f};
        s1[mc] = (floatx4){0.f, 0.f, 0.f, 0.f};
      }
      __builtin_amdgcn_s_setprio(1);
#pragma unroll
      for (int dh = 0; dh < 2; ++dh) {
        const int bo = dh ? bo1 : bo0;
#pragma unroll
        for (int mc = 0; mc < 4; ++mc) {
          short8 ak = *(const short8*)&Ks[cb + (((mc << 4) + l15) << 6) + bo];
          s0[mc] = __builtin_amdgcn_mfma_f32_16x16x32_bf16(ak, qf[0][dh], s0[mc], 0, 0, 0);
          s1[mc] = __builtin_amdgcn_mfma_f32_16x16x32_bf16(ak, qf[1][dh], s1[mc], 0, 0, 0);
        }
      }
      __builtin_amdgcn_s_setprio(0);

      // ---- p = 2^s; mask only on diagonal tiles; truncation-pack ----
      const bool needmask = (k0 + 63 > q0w);
#pragma unroll
      for (int qc = 0; qc < 2; ++qc) {
        const int qg = q0w + (qc << 4) + l15;
        const int rbase = ((qc << 4) + l15) << 6;
#pragma unroll
        for (int mc = 0; mc < 4; ++mc) {
          float p[4];
#pragma unroll
          for (int r = 0; r < 4; ++r) {
            float e = exp2f(qc ? s1[mc][r] : s0[mc][r]);
            if (needmask) {
              int key = k0 + (mc << 4) + (lg << 2) + r;
              e = (key > qg) ? 0.f : e;
            }
            p[r] = e;
          }
          uint2 pk;
          pk.x = (__float_as_uint(p[1]) & 0xFFFF0000u) | (__float_as_uint(p[0]) >> 16);
          pk.y = (__float_as_uint(p[3]) & 0xFFFF0000u) | (__float_as_uint(p[2]) >> 16);
          *(uint2*)&Psw[rbase + pwofs[mc]] = pk;
        }
      }

      // ---- PV: O += P*V ; l += P*ones ----
      short8 pa[2][2];
#pragma unroll
      for (int qc = 0; qc < 2; ++qc) {
        const int rbase = ((qc << 4) + l15) << 6;
#pragma unroll
        for (int kc = 0; kc < 2; ++kc)
          pa[qc][kc] = *(const short8*)&Psw[rbase + profs[kc]];
      }
      __builtin_amdgcn_s_setprio(1);
#pragma unroll
      for (int kc = 0; kc < 2; ++kc) {
        const int bo = kc ? bo1 : bo0;
#pragma unroll
        for (int dc = 0; dc < 4; ++dc) {
          short8 vb = *(const short8*)&Vs[cb + (((dc << 4) + l15) << 6) + bo];
          acc_o[0][dc] = __builtin_amdgcn_mfma_f32_16x16x32_bf16(pa[0][kc], vb, acc_o[0][dc], 0, 0, 0);
          acc_o[1][dc] = __builtin_amdgcn_mfma_f32_16x16x32_bf16(pa[1][kc], vb, acc_o[1][dc], 0, 0, 0);
        }
        acc_l[0] = __builtin_amdgcn_mfma_f32_16x16x32_bf16(pa[0][kc], onef, acc_l[0], 0, 0, 0);
        acc_l[1] = __builtin_amdgcn_mfma_f32_16x16x32_bf16(pa[1][kc], onef, acc_l[1], 0, 0, 0);
      }
      __builtin_amdgcn_s_setprio(0);
    }

    // ---- tile fence: my next-tile loads landed; everyone done reading cur
    asm volatile("s_waitcnt vmcnt(0)" ::: "memory");
    __builtin_amdgcn_s_barrier();
    buf ^= 1;
  }

  // ---- epilogue: Z = O / l ----
#pragma unroll
  for (int qc = 0; qc < 2; ++qc) {
    floatx4 inv;
#pragma unroll
    for (int r = 0; r < 4; ++r) inv[r] = 1.f / acc_l[qc][r];
#pragma unroll
    for (int dc = 0; dc < 4; ++dc)
#pragma unroll
      for (int r = 0; r < 4; ++r) {
        int qg = q0w + (qc << 4) + (lg << 2) + r;
        Z[(((size_t)b << 11) + qg) * 1024 + (n << 6) + (dc << 4) + l15] =
            f2bf(acc_o[qc][dc][r] * inv[r]);
      }
  }
}

// ---------------------------------------------------------------------------
extern "C" void kernel_launch(void* const* d_in, const int* in_sizes, int n_in,
                              void* d_out, int out_size, void* d_ws, size_t ws_size,
                              hipStream_t stream) {
  const float* x   = (const float*)d_in[0];
  const float* W_Q = (const float*)d_in[1];
  const float* b_Q = (const float*)d_in[2];
  const float* W_K = (const float*)d_in[3];
  const float* b_K = (const float*)d_in[4];
  const float* W_V = (const float*)d_in[5];
  const float* b_V = (const float*)d_in[6];
  const float* W_O = (const float*)d_in[7];
  const float* b_O = (const float*)d_in[8];
  float* out = (float*)d_out;

  unsigned short* ws    = (unsigned short*)d_ws;
  unsigned short* BtQKV = ws;                        // [3072][1024]
  unsigned short* Wo_t  = BtQKV + (3u << 20);        // [1024][1024]
  unsigned short* Xb    = Wo_t + (1u << 20);         // [8192][1024]
  unsigned short* Qb    = Xb + (8u << 20);           // [B,N,S,D]
  unsigned short* Kb    = Qb + (8u << 20);
  unsigned short* Vtb   = Kb + (8u << 20);           // [B,N,D,S]
  unsigned short* Zb    = Vtb + (8u << 20);          // [B,S,N*D]

  prep_kernel<<<9216, 256, 0, stream>>>(x, Xb, W_Q, W_K, W_V, BtQKV, W_O, Wo_t);

  gemm128_kernel<0><<<dim3(24, 64), 256, 0, stream>>>(
      Xb, BtQKV, b_Q, b_K, b_V, Qb, Kb, Vtb, nullptr);

  flash8_kernel<<<1024, 256, 0, stream>>>(Qb, Kb, Vtb, Zb);

  gemm128_kernel<1><<<dim3(8, 64), 256, 0, stream>>>(
      Zb, Wo_t, b_O, nullptr, nullptr, nullptr, nullptr, nullptr, out);
}

// Round 4
// 263.380 us; speedup vs baseline: 1.2608x; 1.0436x over previous
//
#include <hip/hip_runtime.h>

// ---------------------------------------------------------------------------
// Round 10: VALU diet + occupancy. Three rounds pinned at ~92-97us with
// VALUBusy ~70% >> MfmaUtil 17% -> per-wave VALU-bound. Cuts: (1) pack via
// v_cvt_pk_bf16_f32 (48 bitops -> 16 instr, RNE); (2) persistent zero C for
// QK^T first MFMA (-32 movs/tile); (3) single-buffer V -> LDS 40KB ->
// 4 blocks/CU = 16 waves (was 3/12). V[kt] issued at tile start, gated by
// the mid-tile vmcnt+barrier; K stays double-buffered. Hoisted Ps pointers.
// B=4, S=2048, NH=16, DH=64, E=1024. fp32 I/O, bf16 compute, fp32 accum.
// ---------------------------------------------------------------------------

typedef __attribute__((ext_vector_type(8))) short short8;
typedef __attribute__((ext_vector_type(4))) float floatx4;

#define SCL 0.1803368801111244f   // (1/8) * log2(e), folded into Q projection

__device__ __forceinline__ unsigned short f2bf(float f) {
  unsigned int x = __float_as_uint(f);
  x += 0x7fffu + ((x >> 16) & 1u);   // RNE
  return (unsigned short)(x >> 16);
}

__device__ __forceinline__ void gload_lds16(const unsigned short* g, unsigned short* lds) {
  __builtin_amdgcn_global_load_lds(
      (const __attribute__((address_space(1))) void*)g,
      (__attribute__((address_space(3))) void*)lds, 16, 0, 0);
}

// ---------------- fused prep: cvt_x + W_QKV transpose + W_O transpose ------
__global__ __launch_bounds__(256) void prep_kernel(
    const float* __restrict__ X,  unsigned short* __restrict__ Xb,
    const float* __restrict__ Wq, const float* __restrict__ Wk,
    const float* __restrict__ Wv, unsigned short* __restrict__ Bt,
    const float* __restrict__ Wo, unsigned short* __restrict__ Wt)
{
  __shared__ unsigned short T[64 * 72];
  const int bid = blockIdx.x, t = threadIdx.x;
  if (bid < 8192) {                                  // ---- x fp32 -> bf16
    int idx = ((bid << 8) + t) << 2;
    float4 f = *(const float4*)(X + idx);
    unsigned short u[4] = { f2bf(f.x), f2bf(f.y), f2bf(f.z), f2bf(f.w) };
    *(uint2*)(Xb + idx) = *(uint2*)u;
  } else if (bid < 8960) {                           // ---- W_{Q,K,V} transpose
    int b2 = bid - 8192;
    int e0 = (b2 & 15) << 6, nn = (b2 >> 4) & 15, proj = b2 >> 8;
    const float* W = (proj == 0) ? Wq : (proj == 1) ? Wk : Wv;
    const float* src = W + ((size_t)nn << 16) + ((size_t)e0 << 6);
#pragma unroll
    for (int rnd = 0; rnd < 4; ++rnd) {
      int off = (rnd << 10) + (t << 2);
      float4 f = *(const float4*)(src + off);
      int r = off >> 6, h = off & 63;
      T[r * 72 + h]     = f2bf(f.x);
      T[r * 72 + h + 1] = f2bf(f.y);
      T[r * 72 + h + 2] = f2bf(f.z);
      T[r * 72 + h + 3] = f2bf(f.w);
    }
    __syncthreads();
    const int h = t >> 2, ck = t & 3;
    size_t orow = ((size_t)((proj << 10) + (nn << 6) + h) << 10) + e0 + (ck << 4);
#pragma unroll
    for (int g = 0; g < 2; ++g) {
      unsigned short v[8];
#pragma unroll
      for (int j = 0; j < 8; ++j) v[j] = T[((ck << 4) + (g << 3) + j) * 72 + h];
      *(int4*)(Bt + orow + (g << 3)) = *(int4*)v;
    }
  } else {                                           // ---- W_O transpose
    int b2 = bid - 8960;
    int e0 = (b2 & 15) << 6, k0 = (b2 >> 4) << 6;
#pragma unroll
    for (int rnd = 0; rnd < 4; ++rnd) {
      int r = (rnd << 4) + (t >> 4);
      int c = (t & 15) << 2;
      float4 f = *(const float4*)(Wo + ((size_t)(k0 + r) << 10) + e0 + c);
      T[r * 72 + c]     = f2bf(f.x);
      T[r * 72 + c + 1] = f2bf(f.y);
      T[r * 72 + c + 2] = f2bf(f.z);
      T[r * 72 + c + 3] = f2bf(f.w);
    }
    __syncthreads();
    const int i = t >> 2, ck = t & 3;
    size_t orow = ((size_t)(e0 + i) << 10) + k0 + (ck << 4);
#pragma unroll
    for (int g = 0; g < 2; ++g) {
      unsigned short v[8];
#pragma unroll
      for (int j = 0; j < 8; ++j) v[j] = T[((ck << 4) + (g << 3) + j) * 72 + i];
      *(int4*)(Wt + orow + (g << 3)) = *(int4*)v;
    }
  }
}

// ---------------- 128x128 MFMA GEMM, BK=64 (round-5, kept) -----------------
template <int MODE>
__global__ __launch_bounds__(256) void gemm128_kernel(
    const unsigned short* __restrict__ A,
    const unsigned short* __restrict__ Bt,
    const float* __restrict__ b0, const float* __restrict__ b1,
    const float* __restrict__ b2,
    unsigned short* __restrict__ Oq, unsigned short* __restrict__ Ok,
    unsigned short* __restrict__ Ov, float* __restrict__ Of)
{
  const int K = 1024;
  __shared__ __align__(16) unsigned short As[8192];   // [128][64] swizzled
  __shared__ __align__(16) unsigned short Bs[8192];
  const int tid = threadIdx.x;
  const int l   = tid & 63, w = tid >> 6;
  const int l15 = l & 15,  lg = l >> 4;
  const int mo  = (w >> 1) << 6, no = (w & 1) << 6;
  const int m0  = blockIdx.y << 7, n0 = blockIdx.x << 7;
  const int srow = l >> 3;
  const int gblk = ((l & 7) ^ srow) << 3;
  const int rsw  = l15 & 7;

  floatx4 acc[4][4];
#pragma unroll
  for (int i = 0; i < 4; ++i)
#pragma unroll
    for (int j = 0; j < 4; ++j) acc[i][j] = (floatx4){0.f, 0.f, 0.f, 0.f};

  for (int k0 = 0; k0 < K; k0 += 64) {
    __syncthreads();
#pragma unroll
    for (int s = 0; s < 4; ++s) {
      const int br = (s << 5) + (w << 3);
      gload_lds16(A  + (size_t)(m0 + br + srow) * K + k0 + gblk, &As[br << 6]);
      gload_lds16(Bt + (size_t)(n0 + br + srow) * K + k0 + gblk, &Bs[br << 6]);
    }
    __syncthreads();
#pragma unroll
    for (int kh = 0; kh < 2; ++kh) {
      const int bo = (((kh << 2) + lg) ^ rsw) << 3;
      short8 af[4], bf[4];
#pragma unroll
      for (int mc = 0; mc < 4; ++mc)
        af[mc] = *(const short8*)&As[((mo + (mc << 4) + l15) << 6) + bo];
#pragma unroll
      for (int nc = 0; nc < 4; ++nc)
        bf[nc] = *(const short8*)&Bs[((no + (nc << 4) + l15) << 6) + bo];
#pragma unroll
      for (int mc = 0; mc < 4; ++mc)
#pragma unroll
        for (int nc = 0; nc < 4; ++nc)
          acc[mc][nc] = __builtin_amdgcn_mfma_f32_16x16x32_bf16(af[mc], bf[nc], acc[mc][nc], 0, 0, 0);
    }
  }

#pragma unroll
  for (int nc = 0; nc < 4; ++nc) {
    int c = n0 + no + (nc << 4) + l15;
    if (MODE == 1) {
      float bv = b0[c];
#pragma unroll
      for (int mc = 0; mc < 4; ++mc)
#pragma unroll
        for (int r = 0; r < 4; ++r) {
          int m = m0 + mo + (mc << 4) + (lg << 2) + r;
          Of[((size_t)m << 10) + c] = acc[mc][nc][r] + bv;
        }
    } else {
      int proj = c >> 10, cc = c & 1023;         // wave-uniform
      int hn = cc >> 6, h = cc & 63;
      const float* bp = (proj == 0) ? b0 : (proj == 1) ? b1 : b2;
      float bv = bp[cc];
      float sc = (proj == 0) ? SCL : 1.0f;
      if (proj < 2) {
        unsigned short* O = (proj == 0) ? Oq : Ok;
#pragma unroll
        for (int mc = 0; mc < 4; ++mc)
#pragma unroll
          for (int r = 0; r < 4; ++r) {
            int m = m0 + mo + (mc << 4) + (lg << 2) + r;
            int bb = m >> 11, ss = m & 2047;
            O[((((size_t)(bb << 4) + hn) << 11) + ss) * 64 + h] = f2bf((acc[mc][nc][r] + bv) * sc);
          }
      } else {                                   // V transposed: Vt[b][n][d][s]
#pragma unroll
        for (int mc = 0; mc < 4; ++mc) {
          int m = m0 + mo + (mc << 4) + (lg << 2);
          int bb = m >> 11, ss = m & 2047;
          unsigned short p0 = f2bf(acc[mc][nc][0] + bv);
          unsigned short p1 = f2bf(acc[mc][nc][1] + bv);
          unsigned short p2 = f2bf(acc[mc][nc][2] + bv);
          unsigned short p3 = f2bf(acc[mc][nc][3] + bv);
          uint2 pk;
          pk.x = (unsigned int)p0 | ((unsigned int)p1 << 16);
          pk.y = (unsigned int)p2 | ((unsigned int)p3 << 16);
          *(uint2*)&Ov[((((size_t)(bb << 4) + hn) << 6) + h) * 2048 + ss] = pk;
        }
      }
    }
  }
}

// ---------------- MFMA flash attention v9: VALU-diet, 40KB LDS -------------
// 1024 blocks x 256 threads (4 waves x 32 q-rows = 128-row q-tile).
// qt = 15-(x>>6): longest blocks first. head = x&63 -> XCD = head%8.
// K double-buffered (16KB); V single-buffered (8KB, issued at tile start,
// gated by mid-tile vmcnt+barrier); Ps 16KB. 40KB -> 4 blocks/CU.
// cvt_pk_bf16_f32 packing; persistent-zero C for QK^T first MFMA.
__global__ __launch_bounds__(256, 4) void flash9_kernel(
    const unsigned short* __restrict__ Q,   // [B,N,S,D], pre-scaled by SCL
    const unsigned short* __restrict__ K,   // [B,N,S,D]
    const unsigned short* __restrict__ Vt,  // [B,N,D,S]
    unsigned short* __restrict__ Z)         // [B,S,N*D]
{
  __shared__ __align__(16) unsigned short Ks[8192];   // 2 x [64 key][64 d] swz
  __shared__ __align__(16) unsigned short Vs[4096];   // [64 d][64 key] swz
  __shared__ __align__(16) unsigned short Ps[8192];   // 4 waves x [32 q][64 k] swz

  const int tid = threadIdx.x;
  const int l   = tid & 63, w = tid >> 6;             // w in {0,1,2,3}
  const int l15 = l & 15,  lg = l >> 4;
  const int x    = blockIdx.x;
  const int qt   = 15 - (x >> 6);                     // 128-row q-tile, longest first
  const int head = x & 63;
  const int n = head & 15, b = head >> 4;
  const size_t hoff = (size_t)head << 17;
  const unsigned short* Qh = Q + hoff;
  const unsigned short* Kh = K + hoff;
  const unsigned short* Vh = Vt + hoff;
  unsigned short* Psw = Ps + (w << 11);

  const int srow8 = l >> 3;
  const int sblk8 = ((l & 7) ^ srow8) << 3;
  const int swz   = l15 & 7;
  const int bo0   = (lg ^ swz) << 3;
  const int bo1   = ((4 + lg) ^ swz) << 3;

  // ---- staging base pointers (hoisted; per-tile adds are uniform) ----
  const unsigned short* gK = Kh + (size_t)(((w << 4) + srow8) << 6) + sblk8;
  const unsigned short* gV = Vh + (size_t)(((w << 4) + srow8) << 11) + sblk8;
  unsigned short* ldsK0 = &Ks[w << 10];               // + (buf<<12), +512 for j=1
  unsigned short* ldsV0 = &Vs[w << 10];               // +512 for j=1

  // ---- Ps pointers (hoisted; row&7 == swz) ----
  //  write key-base mc*16+lg*4 -> chunk16 = 2mc+(lg>>1), half8 = lg&1
  //  read  key-base kc*32+lg*8 -> chunk16 = 4kc+lg
  uint2* pw[2][4];
  const short8* pr[2][2];
#pragma unroll
  for (int qc = 0; qc < 2; ++qc) {
    const int rbase = ((qc << 4) + l15) << 6;
#pragma unroll
    for (int mc = 0; mc < 4; ++mc)
      pw[qc][mc] = (uint2*)&Psw[rbase + (((((mc << 1) + (lg >> 1)) ^ swz) << 3) + ((lg & 1) << 2))];
#pragma unroll
    for (int kc = 0; kc < 2; ++kc)
      pr[qc][kc] = (const short8*)&Psw[rbase + ((((kc << 2) + lg) ^ swz) << 3)];
  }

  short8 onef;
#pragma unroll
  for (int i = 0; i < 8; ++i) onef[i] = (short)0x3F80;   // bf16 1.0

  // persistent zero C-operand (laundered so it is never re-materialized)
  floatx4 z4 = (floatx4){0.f, 0.f, 0.f, 0.f};
  asm volatile("" : "+v"(z4));

  const int q0w = (qt << 7) + (w << 5);                  // wave's 32 rows

  short8 qf[2][2];
#pragma unroll
  for (int qc = 0; qc < 2; ++qc)
#pragma unroll
    for (int dh = 0; dh < 2; ++dh)
      qf[qc][dh] = *(const short8*)(Qh + (size_t)(q0w + (qc << 4) + l15) * 64 + (dh << 5) + (lg << 3));

  floatx4 acc_o[2][4], acc_l[2];
#pragma unroll
  for (int qc = 0; qc < 2; ++qc) {
    acc_l[qc] = (floatx4){0.f, 0.f, 0.f, 0.f};
#pragma unroll
    for (int dc = 0; dc < 4; ++dc) acc_o[qc][dc] = (floatx4){0.f, 0.f, 0.f, 0.f};
  }

  // ---- prologue: stage K-tile 0 into buffer 0 ----
  gload_lds16(gK,       ldsK0);
  gload_lds16(gK + 512, ldsK0 + 512);
  asm volatile("s_waitcnt vmcnt(0)" ::: "memory");
  __builtin_amdgcn_s_barrier();

  int buf = 0;
  const int nkt = (qt << 1) + 2;                       // 64-key tiles
  for (int kt = 0; kt < nkt; ++kt) {
    const int k0 = kt << 6;

    // ---- issue V[kt] (consumed this tile, after mid barrier) ----
    {
      const unsigned short* pV = gV + k0;
      gload_lds16(pV,          ldsV0);
      gload_lds16(pV + 16384,  ldsV0 + 512);
    }
    // ---- issue K[kt+1] into buf^1 (consumed next tile) ----
    if (kt + 1 < nkt) {
      const unsigned short* pK = gK + ((size_t)(kt + 1) << 12);
      unsigned short* d = ldsK0 + ((buf ^ 1) << 12);
      gload_lds16(pK,       d);
      gload_lds16(pK + 512, d + 512);
    }

    const bool active = (k0 <= q0w + 31);
    if (active) {
      const int cb = buf << 12;

      // ---- S^T[key][q] = K * Q^T (first MFMA uses persistent zero C) ----
      floatx4 s0[4], s1[4];
      __builtin_amdgcn_s_setprio(1);
#pragma unroll
      for (int mc = 0; mc < 4; ++mc) {
        short8 ak = *(const short8*)&Ks[cb + (((mc << 4) + l15) << 6) + bo0];
        s0[mc] = __builtin_amdgcn_mfma_f32_16x16x32_bf16(ak, qf[0][0], z4, 0, 0, 0);
        s1[mc] = __builtin_amdgcn_mfma_f32_16x16x32_bf16(ak, qf[1][0], z4, 0, 0, 0);
      }
#pragma unroll
      for (int mc = 0; mc < 4; ++mc) {
        short8 ak = *(const short8*)&Ks[cb + (((mc << 4) + l15) << 6) + bo1];
        s0[mc] = __builtin_amdgcn_mfma_f32_16x16x32_bf16(ak, qf[0][1], s0[mc], 0, 0, 0);
        s1[mc] = __builtin_amdgcn_mfma_f32_16x16x32_bf16(ak, qf[1][1], s1[mc], 0, 0, 0);
      }
      __builtin_amdgcn_s_setprio(0);

      // ---- p = 2^s; mask only on diagonal tiles; cvt_pk pack ----
      const bool needmask = (k0 + 63 > q0w);
#pragma unroll
      for (int qc = 0; qc < 2; ++qc) {
        const int qg = q0w + (qc << 4) + l15;
#pragma unroll
        for (int mc = 0; mc < 4; ++mc) {
          float p[4];
#pragma unroll
          for (int r = 0; r < 4; ++r) {
            float e = exp2f(qc ? s1[mc][r] : s0[mc][r]);
            if (needmask) {
              int key = k0 + (mc << 4) + (lg << 2) + r;
              e = (key > qg) ? 0.f : e;
            }
            p[r] = e;
          }
          uint2 pk;
          asm("v_cvt_pk_bf16_f32 %0, %1, %2" : "=v"(pk.x) : "v"(p[0]), "v"(p[1]));
          asm("v_cvt_pk_bf16_f32 %0, %1, %2" : "=v"(pk.y) : "v"(p[2]), "v"(p[3]));
          *pw[qc][mc] = pk;
        }
      }
    }

    // ---- mid fence: V[kt] + K[kt+1] landed; all waves done reading Ks[buf]
    asm volatile("s_waitcnt vmcnt(0)" ::: "memory");
    __builtin_amdgcn_s_barrier();

    if (active) {
      // ---- PV: O += P*V ; l += P*ones ----
      short8 pa[2][2];
#pragma unroll
      for (int qc = 0; qc < 2; ++qc)
#pragma unroll
        for (int kc = 0; kc < 2; ++kc)
          pa[qc][kc] = *pr[qc][kc];
      __builtin_amdgcn_s_setprio(1);
#pragma unroll
      for (int kc = 0; kc < 2; ++kc) {
        const int bo = kc ? bo1 : bo0;
#pragma unroll
        for (int dc = 0; dc < 4; ++dc) {
          short8 vb = *(const short8*)&Vs[(((dc << 4) + l15) << 6) + bo];
          acc_o[0][dc] = __builtin_amdgcn_mfma_f32_16x16x32_bf16(pa[0][kc], vb, acc_o[0][dc], 0, 0, 0);
          acc_o[1][dc] = __builtin_amdgcn_mfma_f32_16x16x32_bf16(pa[1][kc], vb, acc_o[1][dc], 0, 0, 0);
        }
        acc_l[0] = __builtin_amdgcn_mfma_f32_16x16x32_bf16(pa[0][kc], onef, acc_l[0], 0, 0, 0);
        acc_l[1] = __builtin_amdgcn_mfma_f32_16x16x32_bf16(pa[1][kc], onef, acc_l[1], 0, 0, 0);
      }
      __builtin_amdgcn_s_setprio(0);
    }

    // ---- end fence: all waves done reading Vs before next V issue ----
    __builtin_amdgcn_s_barrier();
    buf ^= 1;
  }

  // ---- epilogue: Z = O / l ----
#pragma unroll
  for (int qc = 0; qc < 2; ++qc) {
    floatx4 inv;
#pragma unroll
    for (int r = 0; r < 4; ++r) inv[r] = 1.f / acc_l[qc][r];
#pragma unroll
    for (int dc = 0; dc < 4; ++dc)
#pragma unroll
      for (int r = 0; r < 4; ++r) {
        int qg = q0w + (qc << 4) + (lg << 2) + r;
        Z[(((size_t)b << 11) + qg) * 1024 + (n << 6) + (dc << 4) + l15] =
            f2bf(acc_o[qc][dc][r] * inv[r]);
      }
  }
}

// ---------------------------------------------------------------------------
extern "C" void kernel_launch(void* const* d_in, const int* in_sizes, int n_in,
                              void* d_out, int out_size, void* d_ws, size_t ws_size,
                              hipStream_t stream) {
  const float* x   = (const float*)d_in[0];
  const float* W_Q = (const float*)d_in[1];
  const float* b_Q = (const float*)d_in[2];
  const float* W_K = (const float*)d_in[3];
  const float* b_K = (const float*)d_in[4];
  const float* W_V = (const float*)d_in[5];
  const float* b_V = (const float*)d_in[6];
  const float* W_O = (const float*)d_in[7];
  const float* b_O = (const float*)d_in[8];
  float* out = (float*)d_out;

  unsigned short* ws    = (unsigned short*)d_ws;
  unsigned short* BtQKV = ws;                        // [3072][1024]
  unsigned short* Wo_t  = BtQKV + (3u << 20);        // [1024][1024]
  unsigned short* Xb    = Wo_t + (1u << 20);         // [8192][1024]
  unsigned short* Qb    = Xb + (8u << 20);           // [B,N,S,D]
  unsigned short* Kb    = Qb + (8u << 20);
  unsigned short* Vtb   = Kb + (8u << 20);           // [B,N,D,S]
  unsigned short* Zb    = Vtb + (8u << 20);          // [B,S,N*D]

  prep_kernel<<<9216, 256, 0, stream>>>(x, Xb, W_Q, W_K, W_V, BtQKV, W_O, Wo_t);

  gemm128_kernel<0><<<dim3(24, 64), 256, 0, stream>>>(
      Xb, BtQKV, b_Q, b_K, b_V, Qb, Kb, Vtb, nullptr);

  flash9_kernel<<<1024, 256, 0, stream>>>(Qb, Kb, Vtb, Zb);

  gemm128_kernel<1><<<dim3(8, 64), 256, 0, stream>>>(
      Zb, Wo_t, b_O, nullptr, nullptr, nullptr, nullptr, nullptr, out);
}